// Round 1
// baseline (251.475 us; speedup 1.0000x reference)
//
#include <hip/hip_runtime.h>

typedef unsigned short u16;
typedef unsigned int u32;
typedef short bf16x8 __attribute__((ext_vector_type(8)));
typedef float f32x4 __attribute__((ext_vector_type(4)));

#define AS1 __attribute__((address_space(1)))
#define AS3 __attribute__((address_space(3)))

// ---- constants for this problem ----
#define NTOK 4096
#define HDIM 512
#define FDIM 2048
#define NEXP 8
#define TOPK 2
#define NASSIGN (NTOK * TOPK)         // 8192
#define NPAD (NASSIGN + NEXP * 128)   // 9216 upper bound on 128-padded rows
#define RBMAX 128                     // > 72 worst-case rowblocks

__device__ __forceinline__ void g2l16(const void* g, void* l) {
  __builtin_amdgcn_global_load_lds((const AS1 u32*)g, (AS3 u32*)l, 16, 0, 0);
}

__device__ __forceinline__ u16 f2bf(float f) {  // RNE fp32 -> bf16
  u32 u = __float_as_uint(f);
  u = (u + 0x7FFFu + ((u >> 16) & 1u)) >> 16;
  return (u16)u;
}

// ---------------- fp32 -> bf16 convert (vectorized) ----------------
__global__ void cvt_kernel(const float* __restrict__ src, u16* __restrict__ dst, int n4) {
  int i = blockIdx.x * blockDim.x + threadIdx.x;
  if (i >= n4) return;
  float4 v = reinterpret_cast<const float4*>(src)[i];
  ushort4 o;
  o.x = f2bf(v.x); o.y = f2bf(v.y); o.z = f2bf(v.z); o.w = f2bf(v.w);
  reinterpret_cast<ushort4*>(dst)[i] = o;
}

// ---------------- router: Wr_eff = W_router @ W_in (fp64) ----------------
__global__ void wreff_kernel(const float* __restrict__ Wr, const float* __restrict__ Win,
                             double* __restrict__ wre) {
  int t = blockIdx.x * blockDim.x + threadIdx.x;  // 4096 threads: e*512+k
  int e = t >> 9, k = t & 511;
  const float* wr = Wr + e * HDIM;
  double a = 0.0;
  for (int j = 0; j < HDIM; ++j) a += (double)wr[j] * (double)Win[j * HDIM + k];
  wre[t] = a;
}

// ---------------- router: logits = x @ Wr_eff^T, softmax, top-2 ----------------
__global__ __launch_bounds__(256) void router_kernel(
    const float* __restrict__ x, const double* __restrict__ wre,
    int* __restrict__ idx, float* __restrict__ wts) {
  __shared__ double lw[NEXP * HDIM];  // 32 KB
  for (int i = threadIdx.x; i < NEXP * HDIM; i += 256) lw[i] = wre[i];
  __syncthreads();
  int n = blockIdx.x * 256 + threadIdx.x;
  const float* xr = x + (size_t)n * HDIM;
  double acc[NEXP] = {};
  for (int k = 0; k < HDIM; ++k) {
    double xv = (double)xr[k];
#pragma unroll
    for (int e = 0; e < NEXP; ++e) acc[e] += xv * lw[e * HDIM + k];
  }
  double mx = acc[0];
#pragma unroll
  for (int e = 1; e < NEXP; ++e) mx = acc[e] > mx ? acc[e] : mx;
  double p[NEXP], se = 0.0;
#pragma unroll
  for (int e = 0; e < NEXP; ++e) { p[e] = exp(acc[e] - mx); se += p[e]; }
  double inv = 1.0 / se;
#pragma unroll
  for (int e = 0; e < NEXP; ++e) p[e] *= inv;
  int i0 = 0; double b0 = p[0];
#pragma unroll
  for (int e = 1; e < NEXP; ++e) if (p[e] > b0) { b0 = p[e]; i0 = e; }
  int i1 = -1; double b1 = -1.0;
#pragma unroll
  for (int e = 0; e < NEXP; ++e) if (e != i0 && p[e] > b1) { b1 = p[e]; i1 = e; }
  // reference: softmax OF the top-2 probabilities (not renormalization)
  double e0 = exp(b0), e1 = exp(b1);
  idx[2 * n] = i0; idx[2 * n + 1] = i1;
  wts[2 * n] = (float)(e0 / (e0 + e1));
  wts[2 * n + 1] = (float)(e1 / (e0 + e1));
}

// ---------------- build per-expert gather lists + rowblock schedule ----------------
__global__ void assign_kernel(const int* __restrict__ idx, int* __restrict__ tok,
                              int* __restrict__ pos, int* __restrict__ rbe,
                              int* __restrict__ rbp, int* __restrict__ nrb) {
  __shared__ int cnt[NEXP], cur[NEXP];
  const int tid = threadIdx.x;
  if (tid < NEXP) cnt[tid] = 0;
  __syncthreads();
  for (int a = tid; a < NASSIGN; a += 256) atomicAdd(&cnt[idx[a]], 1);
  __syncthreads();
  if (tid == 0) {
    int o = 0, n = 0;
    for (int e = 0; e < NEXP; ++e) {
      cur[e] = o;
      int nb = (cnt[e] + 127) >> 7;
      for (int i = 0; i < nb; ++i) { rbe[n] = e; rbp[n] = o + i * 128; ++n; }
      o += nb * 128;
    }
    nrb[0] = n;
  }
  __syncthreads();
  for (int p = tid; p < NPAD; p += 256) tok[p] = 0;  // pad rows -> token 0 (never read back)
  __syncthreads();
  for (int a = tid; a < NASSIGN; a += 256) {
    int e = idx[a];
    int q = atomicAdd(&cur[e], 1);
    tok[q] = a >> 1;
    pos[a] = q;
  }
}

// ---------------- plain BT GEMM: C[M,N] = A[M,K] @ B[N,K]^T (bf16 MFMA) ----------------
template <int STORE_BF16>
__global__ __launch_bounds__(256, 2) void gemm_bt_kernel(
    const u16* __restrict__ A, const u16* __restrict__ B, void* __restrict__ C,
    int M, int N, int K) {
  __shared__ u16 lA[128 * 64];
  __shared__ u16 lB[128 * 64];
  const int tid = threadIdx.x;
  const int w = tid >> 6, l = tid & 63;
  const int m0 = blockIdx.y * 128, n0 = blockIdx.x * 128;
  const int wm = (w >> 1) * 64, wn = (w & 1) * 64;
  const int lr = l >> 3, lc = (l & 7) * 8;
  f32x4 acc[4][4] = {};
  const u16* Ab = A + (size_t)(m0 + w * 32 + lr) * K + lc;
  const u16* Bb = B + (size_t)(n0 + w * 32 + lr) * K + lc;
  for (int kt = 0; kt < K; kt += 64) {
#pragma unroll
    for (int j = 0; j < 4; ++j) {
      g2l16(Ab + (size_t)j * 8 * K + kt, &lA[w * 2048 + j * 512]);
      g2l16(Bb + (size_t)j * 8 * K + kt, &lB[w * 2048 + j * 512]);
    }
    __syncthreads();
#pragma unroll
    for (int kk = 0; kk < 2; ++kk) {
      bf16x8 af[4], bf[4];
      const int ko = kk * 32 + (l >> 4) * 8;
#pragma unroll
      for (int i = 0; i < 4; ++i) af[i] = *(const bf16x8*)&lA[(wm + i * 16 + (l & 15)) * 64 + ko];
#pragma unroll
      for (int j = 0; j < 4; ++j) bf[j] = *(const bf16x8*)&lB[(wn + j * 16 + (l & 15)) * 64 + ko];
#pragma unroll
      for (int i = 0; i < 4; ++i)
#pragma unroll
        for (int j = 0; j < 4; ++j)
          acc[i][j] = __builtin_amdgcn_mfma_f32_16x16x32_bf16(af[i], bf[j], acc[i][j], 0, 0, 0);
    }
    __syncthreads();
  }
  const int cr = (l >> 4) * 4, cc = l & 15;
#pragma unroll
  for (int i = 0; i < 4; ++i)
#pragma unroll
    for (int j = 0; j < 4; ++j)
#pragma unroll
      for (int r = 0; r < 4; ++r) {
        int row = m0 + wm + i * 16 + cr + r;
        int col = n0 + wn + j * 16 + cc;
        if (STORE_BF16)
          ((u16*)C)[(size_t)row * N + col] = f2bf(acc[i][j][r]);
        else
          ((float*)C)[(size_t)row * N + col] = acc[i][j][r];
      }
}

// ---------------- grouped gate+up GEMM with fused SiLU epilogue ----------------
__global__ __launch_bounds__(256, 2) void gateup_kernel(
    const u16* __restrict__ hb, const u16* __restrict__ Wg, const u16* __restrict__ Wu,
    u16* __restrict__ act, const int* __restrict__ tok, const int* __restrict__ rbe,
    const int* __restrict__ rbp, const int* __restrict__ nrb) {
  const int rb = blockIdx.y;
  if (rb >= nrb[0]) return;
  __shared__ u16 lA[128 * 64];
  __shared__ u16 lG[128 * 64];
  __shared__ u16 lU[128 * 64];
  const int e = rbe[rb], p0 = rbp[rb], n0 = blockIdx.x * 128;
  const int tid = threadIdx.x;
  const int w = tid >> 6, l = tid & 63;
  const int wm = (w >> 1) * 64, wn = (w & 1) * 64;
  const int lr = l >> 3, lc = (l & 7) * 8;
  const u16* Bg = Wg + (size_t)e * (FDIM * HDIM) + (size_t)(n0 + w * 32 + lr) * HDIM + lc;
  const u16* Bu = Wu + (size_t)e * (FDIM * HDIM) + (size_t)(n0 + w * 32 + lr) * HDIM + lc;
  int trow[4];
#pragma unroll
  for (int j = 0; j < 4; ++j) trow[j] = tok[p0 + w * 32 + j * 8 + lr];
  f32x4 ag[4][4] = {}, au[4][4] = {};
  for (int kt = 0; kt < HDIM; kt += 64) {
#pragma unroll
    for (int j = 0; j < 4; ++j) {
      g2l16(hb + (size_t)trow[j] * HDIM + kt + lc, &lA[w * 2048 + j * 512]);
      g2l16(Bg + (size_t)j * 8 * HDIM + kt, &lG[w * 2048 + j * 512]);
      g2l16(Bu + (size_t)j * 8 * HDIM + kt, &lU[w * 2048 + j * 512]);
    }
    __syncthreads();
#pragma unroll
    for (int kk = 0; kk < 2; ++kk) {
      bf16x8 af[4], gf[4], uf[4];
      const int ko = kk * 32 + (l >> 4) * 8;
#pragma unroll
      for (int i = 0; i < 4; ++i) af[i] = *(const bf16x8*)&lA[(wm + i * 16 + (l & 15)) * 64 + ko];
#pragma unroll
      for (int j = 0; j < 4; ++j) {
        gf[j] = *(const bf16x8*)&lG[(wn + j * 16 + (l & 15)) * 64 + ko];
        uf[j] = *(const bf16x8*)&lU[(wn + j * 16 + (l & 15)) * 64 + ko];
      }
#pragma unroll
      for (int i = 0; i < 4; ++i)
#pragma unroll
        for (int j = 0; j < 4; ++j) {
          ag[i][j] = __builtin_amdgcn_mfma_f32_16x16x32_bf16(af[i], gf[j], ag[i][j], 0, 0, 0);
          au[i][j] = __builtin_amdgcn_mfma_f32_16x16x32_bf16(af[i], uf[j], au[i][j], 0, 0, 0);
        }
    }
    __syncthreads();
  }
  const int cr = (l >> 4) * 4, cc = l & 15;
#pragma unroll
  for (int i = 0; i < 4; ++i)
#pragma unroll
    for (int j = 0; j < 4; ++j)
#pragma unroll
      for (int r = 0; r < 4; ++r) {
        int prow = p0 + wm + i * 16 + cr + r;
        int col = n0 + wn + j * 16 + cc;
        float g = ag[i][j][r], u = au[i][j][r];
        float s = g / (1.0f + __expf(-g));  // silu
        act[(size_t)prow * FDIM + col] = f2bf(s * u);
      }
}

// ---------------- grouped down GEMM (fp32 out) ----------------
__global__ __launch_bounds__(256, 2) void down_kernel(
    const u16* __restrict__ act, const u16* __restrict__ Wd, float* __restrict__ dout,
    const int* __restrict__ rbe, const int* __restrict__ rbp, const int* __restrict__ nrb) {
  const int rb = blockIdx.y;
  if (rb >= nrb[0]) return;
  __shared__ u16 lA[128 * 64];
  __shared__ u16 lB[128 * 64];
  const int e = rbe[rb], p0 = rbp[rb], n0 = blockIdx.x * 128;
  const int tid = threadIdx.x;
  const int w = tid >> 6, l = tid & 63;
  const int wm = (w >> 1) * 64, wn = (w & 1) * 64;
  const int lr = l >> 3, lc = (l & 7) * 8;
  f32x4 acc[4][4] = {};
  const u16* Ab = act + (size_t)(p0 + w * 32 + lr) * FDIM + lc;
  const u16* Bb = Wd + (size_t)e * (HDIM * FDIM) + (size_t)(n0 + w * 32 + lr) * FDIM + lc;
  for (int kt = 0; kt < FDIM; kt += 64) {
#pragma unroll
    for (int j = 0; j < 4; ++j) {
      g2l16(Ab + (size_t)j * 8 * FDIM + kt, &lA[w * 2048 + j * 512]);
      g2l16(Bb + (size_t)j * 8 * FDIM + kt, &lB[w * 2048 + j * 512]);
    }
    __syncthreads();
#pragma unroll
    for (int kk = 0; kk < 2; ++kk) {
      bf16x8 af[4], bf[4];
      const int ko = kk * 32 + (l >> 4) * 8;
#pragma unroll
      for (int i = 0; i < 4; ++i) af[i] = *(const bf16x8*)&lA[(wm + i * 16 + (l & 15)) * 64 + ko];
#pragma unroll
      for (int j = 0; j < 4; ++j) bf[j] = *(const bf16x8*)&lB[(wn + j * 16 + (l & 15)) * 64 + ko];
#pragma unroll
      for (int i = 0; i < 4; ++i)
#pragma unroll
        for (int j = 0; j < 4; ++j)
          acc[i][j] = __builtin_amdgcn_mfma_f32_16x16x32_bf16(af[i], bf[j], acc[i][j], 0, 0, 0);
    }
    __syncthreads();
  }
  const int cr = (l >> 4) * 4, cc = l & 15;
#pragma unroll
  for (int i = 0; i < 4; ++i)
#pragma unroll
    for (int j = 0; j < 4; ++j)
#pragma unroll
      for (int r = 0; r < 4; ++r) {
        int prow = p0 + wm + i * 16 + cr + r;
        int col = n0 + wn + j * 16 + cc;
        dout[(size_t)prow * HDIM + col] = acc[i][j][r];
      }
}

// ---------------- combine: c[n] = w0*down[pos0] + w1*down[pos1] -> bf16 ----------------
__global__ void combine_kernel(const float* __restrict__ dout, const int* __restrict__ pos,
                               const float* __restrict__ wts, u16* __restrict__ cb) {
  const int n = blockIdx.x, t = threadIdx.x;  // 128 threads, 4 floats each
  const int p0 = pos[2 * n], p1 = pos[2 * n + 1];
  const float w0 = wts[2 * n], w1 = wts[2 * n + 1];
  const float4 a = reinterpret_cast<const float4*>(dout + (size_t)p0 * HDIM)[t];
  const float4 b = reinterpret_cast<const float4*>(dout + (size_t)p1 * HDIM)[t];
  ushort4 o;
  o.x = f2bf(w0 * a.x + w1 * b.x);
  o.y = f2bf(w0 * a.y + w1 * b.y);
  o.z = f2bf(w0 * a.z + w1 * b.z);
  o.w = f2bf(w0 * a.w + w1 * b.w);
  reinterpret_cast<ushort4*>(cb + (size_t)n * HDIM)[t] = o;
}

extern "C" void kernel_launch(void* const* d_in, const int* in_sizes, int n_in,
                              void* d_out, int out_size, void* d_ws, size_t ws_size,
                              hipStream_t stream) {
  const float* x   = (const float*)d_in[0];
  const float* Wi  = (const float*)d_in[1];
  const float* Wr  = (const float*)d_in[2];
  const float* Wg  = (const float*)d_in[3];
  const float* Wu  = (const float*)d_in[4];
  const float* Wd  = (const float*)d_in[5];
  const float* Wo  = (const float*)d_in[6];
  float* out = (float*)d_out;

  char* ws = (char*)d_ws;
  size_t off = 0;
  auto alloc = [&](size_t bytes) -> void* {
    off = (off + 255) & ~(size_t)255;
    void* p = ws + off;
    off += bytes;
    return p;
  };
  u16* xb  = (u16*)alloc((size_t)NTOK * HDIM * 2);
  u16* hb  = (u16*)alloc((size_t)NTOK * HDIM * 2);
  u16* cb  = (u16*)alloc((size_t)NTOK * HDIM * 2);
  u16* Wib = (u16*)alloc((size_t)HDIM * HDIM * 2);
  u16* Wob = (u16*)alloc((size_t)HDIM * HDIM * 2);
  u16* Wgb = (u16*)alloc((size_t)NEXP * FDIM * HDIM * 2);
  u16* Wub = (u16*)alloc((size_t)NEXP * FDIM * HDIM * 2);
  u16* Wdb = (u16*)alloc((size_t)NEXP * HDIM * FDIM * 2);
  u16* actb = (u16*)alloc((size_t)NPAD * FDIM * 2);
  float* dwn = (float*)alloc((size_t)NPAD * HDIM * 4);
  double* wre = (double*)alloc((size_t)NEXP * HDIM * 8);
  int* idx = (int*)alloc((size_t)NASSIGN * 4);
  float* wts = (float*)alloc((size_t)NASSIGN * 4);
  int* tok = (int*)alloc((size_t)NPAD * 4);
  int* pos = (int*)alloc((size_t)NASSIGN * 4);
  int* rbe = (int*)alloc((size_t)RBMAX * 4);
  int* rbp = (int*)alloc((size_t)RBMAX * 4);
  int* nrb = (int*)alloc(256);

  auto cvt = [&](const float* s, u16* d, size_t n) {
    int n4 = (int)(n / 4);
    cvt_kernel<<<(n4 + 255) / 256, 256, 0, stream>>>(s, d, n4);
  };
  cvt(x, xb, (size_t)NTOK * HDIM);
  cvt(Wi, Wib, (size_t)HDIM * HDIM);
  cvt(Wg, Wgb, (size_t)NEXP * FDIM * HDIM);
  cvt(Wu, Wub, (size_t)NEXP * FDIM * HDIM);
  cvt(Wd, Wdb, (size_t)NEXP * HDIM * FDIM);
  cvt(Wo, Wob, (size_t)HDIM * HDIM);

  wreff_kernel<<<(NEXP * HDIM) / 256, 256, 0, stream>>>(Wr, Wi, wre);
  // h = x @ W_in^T (bf16)
  gemm_bt_kernel<1><<<dim3(HDIM / 128, NTOK / 128), 256, 0, stream>>>(xb, Wib, hb, NTOK, HDIM, HDIM);
  // routing (fp64 composed logits)
  router_kernel<<<NTOK / 256, 256, 0, stream>>>(x, wre, idx, wts);
  assign_kernel<<<1, 256, 0, stream>>>(idx, tok, pos, rbe, rbp, nrb);
  // experts
  gateup_kernel<<<dim3(FDIM / 128, 72), 256, 0, stream>>>(hb, Wgb, Wub, actb, tok, rbe, rbp, nrb);
  down_kernel<<<dim3(HDIM / 128, 72), 256, 0, stream>>>(actb, Wdb, dwn, rbe, rbp, nrb);
  combine_kernel<<<NTOK, 128, 0, stream>>>(dwn, pos, wts, cb);
  // out = combined @ W_out^T (fp32)
  gemm_bt_kernel<0><<<dim3(HDIM / 128, NTOK / 128), 256, 0, stream>>>(cb, Wob, out, NTOK, HDIM, HDIM);
}

// Round 2
// 218.497 us; speedup vs baseline: 1.1509x; 1.1509x over previous
//
#include <hip/hip_runtime.h>

typedef unsigned short u16;
typedef unsigned int u32;
typedef short bf16x8 __attribute__((ext_vector_type(8)));
typedef float f32x4 __attribute__((ext_vector_type(4)));

#define AS1 __attribute__((address_space(1)))
#define AS3 __attribute__((address_space(3)))

#define NTOK 4096
#define HDIM 512
#define FDIM 2048
#define NEXP 8
#define NASSIGN (NTOK * 2)
#define NPAD (NASSIGN + NEXP * 128)
#define RBMAX 128

__device__ __forceinline__ void g2l16(const void* g, void* l) {
  __builtin_amdgcn_global_load_lds((const AS1 u32*)g, (AS3 u32*)l, 16, 0, 0);
}
__device__ __forceinline__ u16 f2bf(float f) {
  u32 u = __float_as_uint(f);
  u = (u + 0x7FFFu + ((u >> 16) & 1u)) >> 16;
  return (u16)u;
}
__device__ __forceinline__ float bf2f(u16 h) { return __uint_as_float(((u32)h) << 16); }

#define VMBAR() do { asm volatile("s_waitcnt vmcnt(0)" ::: "memory"); __builtin_amdgcn_s_barrier(); } while (0)

// ---------------- prep1: cvt x/Wi/Wo + Wr_eff = W_router @ W_in (fp64) ----------------
__global__ __launch_bounds__(512, 4) void prep1_kernel(
    const float* __restrict__ x, const float* __restrict__ Wi, const float* __restrict__ Wo,
    const float* __restrict__ Wr, u16* __restrict__ xb, u16* __restrict__ Wib,
    u16* __restrict__ Wob, double* __restrict__ wre) {
  const int b = blockIdx.x, tid = threadIdx.x;
  if (b < 640) {
    const float* s; u16* d; int base;
    if (b < 512) { s = x; d = xb; base = b * 1024; }
    else if (b < 576) { s = Wi; d = Wib; base = (b - 512) * 1024; }
    else { s = Wo; d = Wob; base = (b - 576) * 1024; }
#pragma unroll
    for (int i = 0; i < 2; ++i) {
      const int ix = base + tid + i * 512;
      const float4 v = ((const float4*)s)[ix];
      ushort4 o; o.x = f2bf(v.x); o.y = f2bf(v.y); o.z = f2bf(v.z); o.w = f2bf(v.w);
      ((ushort4*)d)[ix] = o;
    }
  } else {
    const int t = (b - 640) * 512 + tid;  // e*512+k
    const int e = t >> 9, k = t & 511;
    const float* wr = Wr + e * HDIM;
    double a = 0.0;
    for (int j = 0; j < HDIM; ++j) a += (double)wr[j] * (double)Wi[j * HDIM + k];
    wre[t] = a;
  }
}

// ---------------- shared 128x128 BT GEMM body (2-phase dbuf, swizzled) ----------------
template <int SB, int NT>
__device__ __forceinline__ void gemm128_body(
    const u16* __restrict__ A, const u16* __restrict__ B, void* __restrict__ C,
    int m0, int n0, int N, int K, u16* sm, int tid) {
  u16 *lA0 = sm, *lA1 = sm + 8192, *lB0 = sm + 16384, *lB1 = sm + 24576;
  const int w = tid >> 6, l = tid & 63;
  const int wm = (w >> 2) * 64, wn = (w & 3) * 32;
  const int lm = l & 15, lk = (l >> 4) * 8, xr = (l & 7) << 3;
  const int sr = l >> 3, sc = ((l & 7) ^ sr) * 8;
  const u16* As = A + (size_t)(m0 + w * 8 + sr) * K + sc;
  const u16* Bs = B + (size_t)(n0 + w * 8 + sr) * K + sc;
  f32x4 acc[4][2] = {};
  auto STG = [&](u16* dA, u16* dB, int kt) {
    g2l16(As + kt, dA + w * 512);
    g2l16(As + (size_t)64 * K + kt, dA + 4096 + w * 512);
    g2l16(Bs + kt, dB + w * 512);
    g2l16(Bs + (size_t)64 * K + kt, dB + 4096 + w * 512);
  };
  auto CMP = [&](const u16* a_, const u16* b_) {
#pragma unroll
    for (int kk = 0; kk < 2; ++kk) {
      const int ko = (kk * 32 + lk) ^ xr;
      bf16x8 af[4], bf[2];
#pragma unroll
      for (int i = 0; i < 4; ++i) af[i] = *(const bf16x8*)(a_ + (wm + i * 16 + lm) * 64 + ko);
#pragma unroll
      for (int j = 0; j < 2; ++j) bf[j] = *(const bf16x8*)(b_ + (wn + j * 16 + lm) * 64 + ko);
#pragma unroll
      for (int i = 0; i < 4; ++i)
#pragma unroll
        for (int j = 0; j < 2; ++j)
          acc[i][j] = __builtin_amdgcn_mfma_f32_16x16x32_bf16(af[i], bf[j], acc[i][j], 0, 0, 0);
    }
  };
  STG(lA0, lB0, 0);
  VMBAR();
  for (int t = 0; t < NT; t += 2) {
    if (t + 1 < NT) STG(lA1, lB1, (t + 1) * 64);
    CMP(lA0, lB0);
    VMBAR();
    if (t + 2 < NT) STG(lA0, lB0, (t + 2) * 64);
    CMP(lA1, lB1);
    VMBAR();
  }
  const int cr = (l >> 4) * 4, cc = lm;
#pragma unroll
  for (int i = 0; i < 4; ++i)
#pragma unroll
    for (int j = 0; j < 2; ++j)
#pragma unroll
      for (int r = 0; r < 4; ++r) {
        const size_t o = (size_t)(m0 + wm + i * 16 + cr + r) * N + n0 + wn + j * 16 + cc;
        if (SB) ((u16*)C)[o] = f2bf(acc[i][j][r]);
        else ((float*)C)[o] = acc[i][j][r];
      }
}

// ---------------- prep2: router + in-proj GEMM + big weight cvt (fused) ----------------
__global__ __launch_bounds__(512, 4) void prep2_kernel(
    const float* __restrict__ x, const double* __restrict__ wre,
    const u16* __restrict__ xb, const u16* __restrict__ Wib,
    const float* __restrict__ Wg, const float* __restrict__ Wu, const float* __restrict__ Wd,
    u16* __restrict__ hb, u16* __restrict__ Wgb, u16* __restrict__ Wub, u16* __restrict__ Wdb,
    int* __restrict__ idx, float* __restrict__ wts) {
  __shared__ __align__(16) u16 pp[32768];
  const int b = blockIdx.x, tid = threadIdx.x;
  if (b < 8) {
    double* lw = (double*)pp;  // 32 KB
    for (int i = tid; i < NEXP * HDIM; i += 512) lw[i] = wre[i];
    __syncthreads();
    const int n = b * 512 + tid;
    const float* xr = x + (size_t)n * HDIM;
    double acc[NEXP] = {};
    for (int k4 = 0; k4 < HDIM / 4; ++k4) {
      const float4 xv = ((const float4*)xr)[k4];
      const float xc[4] = {xv.x, xv.y, xv.z, xv.w};
#pragma unroll
      for (int c = 0; c < 4; ++c) {
        const double xd = (double)xc[c];
#pragma unroll
        for (int e = 0; e < NEXP; ++e) acc[e] += xd * lw[e * HDIM + k4 * 4 + c];
      }
    }
    double mx = acc[0];
#pragma unroll
    for (int e = 1; e < NEXP; ++e) mx = acc[e] > mx ? acc[e] : mx;
    double p[NEXP], se = 0.0;
#pragma unroll
    for (int e = 0; e < NEXP; ++e) { p[e] = exp(acc[e] - mx); se += p[e]; }
    const double inv = 1.0 / se;
#pragma unroll
    for (int e = 0; e < NEXP; ++e) p[e] *= inv;
    int i0 = 0; double b0 = p[0];
#pragma unroll
    for (int e = 1; e < NEXP; ++e) if (p[e] > b0) { b0 = p[e]; i0 = e; }
    int i1 = -1; double b1 = -1.0;
#pragma unroll
    for (int e = 0; e < NEXP; ++e) if (e != i0 && p[e] > b1) { b1 = p[e]; i1 = e; }
    const double e0 = exp(b0), e1 = exp(b1);
    idx[2 * n] = i0; idx[2 * n + 1] = i1;
    wts[2 * n] = (float)(e0 / (e0 + e1));
    wts[2 * n + 1] = (float)(e1 / (e0 + e1));
  } else if (b < 136) {
    const int g = b - 8;  // in-proj: h = x @ W_in^T
    gemm128_body<1, 8>(xb, Wib, hb, (g >> 2) * 128, (g & 3) * 128, HDIM, HDIM, pp, tid);
  } else {
    const int cb = b - 136, which = cb >> 9, lb = cb & 511;
    const float* s = which == 0 ? Wg : which == 1 ? Wu : Wd;
    u16* d = which == 0 ? Wgb : which == 1 ? Wub : Wdb;
    const int base = lb * 4096 + tid;
#pragma unroll
    for (int i = 0; i < 8; ++i) {
      const int ix = base + i * 512;
      const float4 v = ((const float4*)s)[ix];
      ushort4 o; o.x = f2bf(v.x); o.y = f2bf(v.y); o.z = f2bf(v.z); o.w = f2bf(v.w);
      ((ushort4*)d)[ix] = o;
    }
  }
}

// ---------------- build per-expert gather lists + rowblock schedule ----------------
__global__ void assign_kernel(const int* __restrict__ idx, int* __restrict__ tok,
                              int* __restrict__ pos, int* __restrict__ rbe,
                              int* __restrict__ rbp, int* __restrict__ nrb) {
  __shared__ int cnt[NEXP], cur[NEXP];
  const int tid = threadIdx.x;
  if (tid < NEXP) cnt[tid] = 0;
  __syncthreads();
  for (int a = tid; a < NASSIGN; a += 256) atomicAdd(&cnt[idx[a]], 1);
  __syncthreads();
  if (tid == 0) {
    int o = 0, n = 0;
    for (int e = 0; e < NEXP; ++e) {
      cur[e] = o;
      const int nb = (cnt[e] + 127) >> 7;
      for (int i = 0; i < nb; ++i) { rbe[n] = e; rbp[n] = o + i * 128; ++n; }
      o += nb * 128;
    }
    nrb[0] = n;
  }
  __syncthreads();
  for (int p = tid; p < NPAD; p += 256) tok[p] = 0;  // pad rows -> token 0 (never read back)
  __syncthreads();
  for (int a = tid; a < NASSIGN; a += 256) {
    const int e = idx[a];
    const int q = atomicAdd(&cur[e], 1);
    tok[q] = a >> 1;
    pos[a] = q;
  }
}

// ---------------- grouped gate+up GEMM, fused SiLU (2-phase dbuf, swizzled) ----------------
__global__ __launch_bounds__(512, 2) void gateup_kernel(
    const u16* __restrict__ hb, const u16* __restrict__ Wg, const u16* __restrict__ Wu,
    u16* __restrict__ act, const int* __restrict__ tok, const int* __restrict__ rbe,
    const int* __restrict__ rbp, const int* __restrict__ nrb) {
  const int rb = blockIdx.y;
  if (rb >= nrb[0]) return;
  __shared__ __align__(16) u16 sm[49152];  // 96 KB
  u16 *lA0 = sm, *lA1 = sm + 8192, *lG0 = sm + 16384, *lG1 = sm + 24576,
      *lU0 = sm + 32768, *lU1 = sm + 40960;
  const int e = rbe[rb], p0 = rbp[rb], n0 = blockIdx.x * 128;
  const int tid = threadIdx.x, w = tid >> 6, l = tid & 63;
  const int wm = (w >> 2) * 64, wn = (w & 3) * 32;
  const int lm = l & 15, lk = (l >> 4) * 8, xr = (l & 7) << 3;
  const int sr = l >> 3, sc = ((l & 7) ^ sr) * 8;
  const u16* A0 = hb + (size_t)tok[p0 + w * 8 + sr] * HDIM + sc;
  const u16* A1 = hb + (size_t)tok[p0 + 64 + w * 8 + sr] * HDIM + sc;
  const u16* G0 = Wg + (size_t)e * FDIM * HDIM + (size_t)(n0 + w * 8 + sr) * HDIM + sc;
  const u16* G1 = G0 + (size_t)64 * HDIM;
  const u16* U0 = Wu + (size_t)e * FDIM * HDIM + (size_t)(n0 + w * 8 + sr) * HDIM + sc;
  const u16* U1 = U0 + (size_t)64 * HDIM;
  f32x4 ag[4][2] = {}, au[4][2] = {};
  auto STG = [&](u16* dA, u16* dG, u16* dU, int kt) {
    g2l16(A0 + kt, dA + w * 512);
    g2l16(A1 + kt, dA + 4096 + w * 512);
    g2l16(G0 + kt, dG + w * 512);
    g2l16(G1 + kt, dG + 4096 + w * 512);
    g2l16(U0 + kt, dU + w * 512);
    g2l16(U1 + kt, dU + 4096 + w * 512);
  };
  auto CMP = [&](const u16* a_, const u16* g_, const u16* u_) {
#pragma unroll
    for (int kk = 0; kk < 2; ++kk) {
      const int ko = (kk * 32 + lk) ^ xr;
      bf16x8 af[4], gf[2], uf[2];
#pragma unroll
      for (int i = 0; i < 4; ++i) af[i] = *(const bf16x8*)(a_ + (wm + i * 16 + lm) * 64 + ko);
#pragma unroll
      for (int j = 0; j < 2; ++j) {
        gf[j] = *(const bf16x8*)(g_ + (wn + j * 16 + lm) * 64 + ko);
        uf[j] = *(const bf16x8*)(u_ + (wn + j * 16 + lm) * 64 + ko);
      }
#pragma unroll
      for (int i = 0; i < 4; ++i)
#pragma unroll
        for (int j = 0; j < 2; ++j) {
          ag[i][j] = __builtin_amdgcn_mfma_f32_16x16x32_bf16(af[i], gf[j], ag[i][j], 0, 0, 0);
          au[i][j] = __builtin_amdgcn_mfma_f32_16x16x32_bf16(af[i], uf[j], au[i][j], 0, 0, 0);
        }
    }
  };
  STG(lA0, lG0, lU0, 0);
  VMBAR();
#pragma unroll
  for (int t = 0; t < 8; t += 2) {
    if (t + 1 < 8) STG(lA1, lG1, lU1, (t + 1) * 64);
    CMP(lA0, lG0, lU0);
    VMBAR();
    if (t + 2 < 8) STG(lA0, lG0, lU0, (t + 2) * 64);
    CMP(lA1, lG1, lU1);
    VMBAR();
  }
  const int cr = (l >> 4) * 4, cc = lm;
#pragma unroll
  for (int i = 0; i < 4; ++i)
#pragma unroll
    for (int j = 0; j < 2; ++j)
#pragma unroll
      for (int r = 0; r < 4; ++r) {
        const float g = ag[i][j][r], u = au[i][j][r];
        const float s = g / (1.0f + __expf(-g));
        act[(size_t)(p0 + wm + i * 16 + cr + r) * FDIM + n0 + wn + j * 16 + cc] = f2bf(s * u);
      }
}

// ---------------- grouped down GEMM 128x256 (2-phase dbuf, swizzled, bf16 out) ----------------
__global__ __launch_bounds__(512, 2) void down_kernel(
    const u16* __restrict__ act, const u16* __restrict__ Wd, u16* __restrict__ dwn,
    const int* __restrict__ rbe, const int* __restrict__ rbp, const int* __restrict__ nrb) {
  const int rb = blockIdx.y;
  if (rb >= nrb[0]) return;
  __shared__ __align__(16) u16 sm[49152];  // 96 KB
  u16 *lA0 = sm, *lA1 = sm + 8192, *lB0 = sm + 16384, *lB1 = sm + 32768;
  const int e = rbe[rb], p0 = rbp[rb], n0 = blockIdx.x * 256;
  const int tid = threadIdx.x, w = tid >> 6, l = tid & 63;
  const int wm = (w >> 2) * 64, wn = (w & 3) * 64;
  const int lm = l & 15, lk = (l >> 4) * 8, xr = (l & 7) << 3;
  const int sr = l >> 3, sc = ((l & 7) ^ sr) * 8;
  const u16* As = act + (size_t)(p0 + w * 8 + sr) * FDIM + sc;
  const u16* Bs = Wd + (size_t)e * HDIM * FDIM + (size_t)(n0 + w * 8 + sr) * FDIM + sc;
  f32x4 acc[4][4] = {};
  auto STG = [&](u16* dA, u16* dB, int kt) {
    g2l16(As + kt, dA + w * 512);
    g2l16(As + (size_t)64 * FDIM + kt, dA + 4096 + w * 512);
#pragma unroll
    for (int c = 0; c < 4; ++c)
      g2l16(Bs + (size_t)(64 * c) * FDIM + kt, dB + c * 4096 + w * 512);
  };
  auto CMP = [&](const u16* a_, const u16* b_) {
#pragma unroll
    for (int kk = 0; kk < 2; ++kk) {
      const int ko = (kk * 32 + lk) ^ xr;
      bf16x8 af[4], bf[4];
#pragma unroll
      for (int i = 0; i < 4; ++i) af[i] = *(const bf16x8*)(a_ + (wm + i * 16 + lm) * 64 + ko);
#pragma unroll
      for (int j = 0; j < 4; ++j) bf[j] = *(const bf16x8*)(b_ + (wn + j * 16 + lm) * 64 + ko);
#pragma unroll
      for (int i = 0; i < 4; ++i)
#pragma unroll
        for (int j = 0; j < 4; ++j)
          acc[i][j] = __builtin_amdgcn_mfma_f32_16x16x32_bf16(af[i], bf[j], acc[i][j], 0, 0, 0);
    }
  };
  STG(lA0, lB0, 0);
  VMBAR();
  for (int t = 0; t < 32; t += 2) {
    if (t + 1 < 32) STG(lA1, lB1, (t + 1) * 64);
    CMP(lA0, lB0);
    VMBAR();
    if (t + 2 < 32) STG(lA0, lB0, (t + 2) * 64);
    CMP(lA1, lB1);
    VMBAR();
  }
  const int cr = (l >> 4) * 4, cc = lm;
#pragma unroll
  for (int i = 0; i < 4; ++i)
#pragma unroll
    for (int j = 0; j < 4; ++j)
#pragma unroll
      for (int r = 0; r < 4; ++r)
        dwn[(size_t)(p0 + wm + i * 16 + cr + r) * HDIM + n0 + wn + j * 16 + cc] = f2bf(acc[i][j][r]);
}

// ---------------- combine: c[n] = w0*down[pos0] + w1*down[pos1] (bf16 in/out) ----------------
__global__ void combine_kernel(const u16* __restrict__ dwn, const int* __restrict__ pos,
                               const float* __restrict__ wts, u16* __restrict__ cb) {
  const int n = blockIdx.x, t = threadIdx.x;  // 128 threads x 4 elems
  const int p0 = pos[2 * n], p1 = pos[2 * n + 1];
  const float w0 = wts[2 * n], w1 = wts[2 * n + 1];
  const ushort4 a = ((const ushort4*)(dwn + (size_t)p0 * HDIM))[t];
  const ushort4 b = ((const ushort4*)(dwn + (size_t)p1 * HDIM))[t];
  ushort4 o;
  o.x = f2bf(w0 * bf2f(a.x) + w1 * bf2f(b.x));
  o.y = f2bf(w0 * bf2f(a.y) + w1 * bf2f(b.y));
  o.z = f2bf(w0 * bf2f(a.z) + w1 * bf2f(b.z));
  o.w = f2bf(w0 * bf2f(a.w) + w1 * bf2f(b.w));
  ((ushort4*)(cb + (size_t)n * HDIM))[t] = o;
}

// ---------------- out-proj GEMM (fp32 out) ----------------
__global__ __launch_bounds__(512, 4) void out_gemm_kernel(
    const u16* __restrict__ cb, const u16* __restrict__ Wob, float* __restrict__ out) {
  __shared__ __align__(16) u16 sm[32768];  // 64 KB
  gemm128_body<0, 8>(cb, Wob, out, blockIdx.y * 128, blockIdx.x * 128, HDIM, HDIM, sm, threadIdx.x);
}

extern "C" void kernel_launch(void* const* d_in, const int* in_sizes, int n_in,
                              void* d_out, int out_size, void* d_ws, size_t ws_size,
                              hipStream_t stream) {
  const float* x  = (const float*)d_in[0];
  const float* Wi = (const float*)d_in[1];
  const float* Wr = (const float*)d_in[2];
  const float* Wg = (const float*)d_in[3];
  const float* Wu = (const float*)d_in[4];
  const float* Wd = (const float*)d_in[5];
  const float* Wo = (const float*)d_in[6];
  float* out = (float*)d_out;

  char* ws = (char*)d_ws;
  size_t off = 0;
  auto alloc = [&](size_t bytes) -> void* {
    off = (off + 255) & ~(size_t)255;
    void* p = ws + off;
    off += bytes;
    return p;
  };
  u16* xb  = (u16*)alloc((size_t)NTOK * HDIM * 2);
  u16* hb  = (u16*)alloc((size_t)NTOK * HDIM * 2);
  u16* cb  = (u16*)alloc((size_t)NTOK * HDIM * 2);
  u16* Wib = (u16*)alloc((size_t)HDIM * HDIM * 2);
  u16* Wob = (u16*)alloc((size_t)HDIM * HDIM * 2);
  u16* Wgb = (u16*)alloc((size_t)NEXP * FDIM * HDIM * 2);
  u16* Wub = (u16*)alloc((size_t)NEXP * FDIM * HDIM * 2);
  u16* Wdb = (u16*)alloc((size_t)NEXP * HDIM * FDIM * 2);
  u16* actb = (u16*)alloc((size_t)NPAD * FDIM * 2);
  u16* dwn = (u16*)alloc((size_t)NPAD * HDIM * 2);
  double* wre = (double*)alloc((size_t)NEXP * HDIM * 8);
  int* idx = (int*)alloc((size_t)NASSIGN * 4);
  float* wts = (float*)alloc((size_t)NASSIGN * 4);
  int* tok = (int*)alloc((size_t)NPAD * 4);
  int* pos = (int*)alloc((size_t)NASSIGN * 4);
  int* rbe = (int*)alloc((size_t)RBMAX * 4);
  int* rbp = (int*)alloc((size_t)RBMAX * 4);
  int* nrb = (int*)alloc(256);

  prep1_kernel<<<648, 512, 0, stream>>>(x, Wi, Wo, Wr, xb, Wib, Wob, wre);
  prep2_kernel<<<1672, 512, 0, stream>>>(x, wre, xb, Wib, Wg, Wu, Wd, hb, Wgb, Wub, Wdb, idx, wts);
  assign_kernel<<<1, 256, 0, stream>>>(idx, tok, pos, rbe, rbp, nrb);
  gateup_kernel<<<dim3(16, 72), 512, 0, stream>>>(hb, Wgb, Wub, actb, tok, rbe, rbp, nrb);
  down_kernel<<<dim3(2, 72), 512, 0, stream>>>(actb, Wdb, dwn, rbe, rbp, nrb);
  combine_kernel<<<NTOK, 128, 0, stream>>>(dwn, pos, wts, cb);
  out_gemm_kernel<<<dim3(4, 32), 512, 0, stream>>>(cb, Wob, out);
}

// Round 3
// 218.188 us; speedup vs baseline: 1.1526x; 1.0014x over previous
//
#include <hip/hip_runtime.h>

typedef unsigned short u16;
typedef unsigned int u32;
typedef short bf16x8 __attribute__((ext_vector_type(8)));
typedef float f32x4 __attribute__((ext_vector_type(4)));

#define AS1 __attribute__((address_space(1)))
#define AS3 __attribute__((address_space(3)))

#define NTOK 4096
#define HDIM 512
#define FDIM 2048
#define NEXP 8
#define NASSIGN (NTOK * 2)
#define NPAD (NASSIGN + NEXP * 128)
#define RBMAX 128

__device__ __forceinline__ void g2l16(const void* g, void* l) {
  __builtin_amdgcn_global_load_lds((const AS1 u32*)g, (AS3 u32*)l, 16, 0, 0);
}
__device__ __forceinline__ u16 f2bf(float f) {
  u32 u = __float_as_uint(f);
  u = (u + 0x7FFFu + ((u >> 16) & 1u)) >> 16;
  return (u16)u;
}
__device__ __forceinline__ float bf2f(u16 h) { return __uint_as_float(((u32)h) << 16); }

#define WAITV6() asm volatile("s_waitcnt vmcnt(6)" ::: "memory")
#define WAITV4() asm volatile("s_waitcnt vmcnt(4)" ::: "memory")
#define WAITV0() asm volatile("s_waitcnt vmcnt(0)" ::: "memory")
#define BAR() __builtin_amdgcn_s_barrier()
#define VMBAR() do { WAITV0(); BAR(); } while (0)

// ---------------- cvtall: fp32 -> bf16 for all tensors (no LDS, full occupancy) ----------------
// float4 segment boundaries: x 524288 | Wi 65536 | Wo 65536 | Wg/Wu/Wd 2097152 each
__global__ __launch_bounds__(256) void cvtall_kernel(
    const float* __restrict__ x, const float* __restrict__ Wi, const float* __restrict__ Wo,
    const float* __restrict__ Wg, const float* __restrict__ Wu, const float* __restrict__ Wd,
    u16* __restrict__ xb, u16* __restrict__ Wib, u16* __restrict__ Wob,
    u16* __restrict__ Wgb, u16* __restrict__ Wub, u16* __restrict__ Wdb) {
  const int gid = blockIdx.x * 256 + threadIdx.x;
  const int S = 6784 * 256;  // 1,736,704
#pragma unroll
  for (int k = 0; k < 4; ++k) {
    const int i = gid + k * S;
    const float* s; u16* d; int o;
    if (i < 524288) { s = x; d = xb; o = i; }
    else if (i < 589824) { s = Wi; d = Wib; o = i - 524288; }
    else if (i < 655360) { s = Wo; d = Wob; o = i - 589824; }
    else if (i < 2752512) { s = Wg; d = Wgb; o = i - 655360; }
    else if (i < 4849664) { s = Wu; d = Wub; o = i - 2752512; }
    else { s = Wd; d = Wdb; o = i - 4849664; }
    const float4 v = ((const float4*)s)[o];
    ushort4 t; t.x = f2bf(v.x); t.y = f2bf(v.y); t.z = f2bf(v.z); t.w = f2bf(v.w);
    ((ushort4*)d)[o] = t;
  }
}

// ---------------- Wr_eff = W_router @ W_in (fp64, exact routing) ----------------
__global__ __launch_bounds__(256) void wreff_kernel(
    const float* __restrict__ Wr, const float* __restrict__ Wi, double* __restrict__ wre) {
  const int t = blockIdx.x * 256 + threadIdx.x;  // e*512+k
  const int e = t >> 9, k = t & 511;
  const float* wr = Wr + e * HDIM;
  double a = 0.0;
  for (int j = 0; j < HDIM; j += 8) {
#pragma unroll
    for (int u = 0; u < 8; ++u) a += (double)wr[j + u] * (double)Wi[(j + u) * HDIM + k];
  }
  wre[t] = a;
}

// ---------------- router: logits = x @ Wr_eff^T (fp64), softmax, top-2 ----------------
__global__ __launch_bounds__(256) void router_kernel(
    const float* __restrict__ x, const double* __restrict__ wre,
    int* __restrict__ idx, float* __restrict__ wts) {
  __shared__ double lw[NEXP * HDIM];  // 32 KB
  for (int i = threadIdx.x; i < NEXP * HDIM; i += 256) lw[i] = wre[i];
  __syncthreads();
  const int n = blockIdx.x * 256 + threadIdx.x;
  const float* xr = x + (size_t)n * HDIM;
  double acc[NEXP] = {};
  for (int k4 = 0; k4 < HDIM / 4; ++k4) {
    const float4 xv = ((const float4*)xr)[k4];
    const float xc[4] = {xv.x, xv.y, xv.z, xv.w};
#pragma unroll
    for (int c = 0; c < 4; ++c) {
      const double xd = (double)xc[c];
#pragma unroll
      for (int e = 0; e < NEXP; ++e) acc[e] += xd * lw[e * HDIM + k4 * 4 + c];
    }
  }
  double mx = acc[0];
#pragma unroll
  for (int e = 1; e < NEXP; ++e) mx = acc[e] > mx ? acc[e] : mx;
  double p[NEXP], se = 0.0;
#pragma unroll
  for (int e = 0; e < NEXP; ++e) { p[e] = exp(acc[e] - mx); se += p[e]; }
  const double inv = 1.0 / se;
#pragma unroll
  for (int e = 0; e < NEXP; ++e) p[e] *= inv;
  int i0 = 0; double b0 = p[0];
#pragma unroll
  for (int e = 1; e < NEXP; ++e) if (p[e] > b0) { b0 = p[e]; i0 = e; }
  int i1 = -1; double b1 = -1.0;
#pragma unroll
  for (int e = 0; e < NEXP; ++e) if (e != i0 && p[e] > b1) { b1 = p[e]; i1 = e; }
  const double e0 = exp(b0), e1 = exp(b1);  // softmax OF the top-2 probabilities
  idx[2 * n] = i0; idx[2 * n + 1] = i1;
  wts[2 * n] = (float)(e0 / (e0 + e1));
  wts[2 * n + 1] = (float)(e1 / (e0 + e1));
}

// ---------------- per-expert gather lists + 128-padded rowblock schedule ----------------
__global__ void assign_kernel(const int* __restrict__ idx, int* __restrict__ tok,
                              int* __restrict__ pos, int* __restrict__ rbe,
                              int* __restrict__ rbp, int* __restrict__ nrb) {
  __shared__ int cnt[NEXP], cur[NEXP];
  const int tid = threadIdx.x;
  if (tid < NEXP) cnt[tid] = 0;
  __syncthreads();
  for (int a = tid; a < NASSIGN; a += 256) atomicAdd(&cnt[idx[a]], 1);
  __syncthreads();
  if (tid == 0) {
    int o = 0, n = 0;
    for (int e = 0; e < NEXP; ++e) {
      cur[e] = o;
      const int nb = (cnt[e] + 127) >> 7;
      for (int i = 0; i < nb; ++i) { rbe[n] = e; rbp[n] = o + i * 128; ++n; }
      o += nb * 128;
    }
    nrb[0] = n;
  }
  __syncthreads();
  for (int p = tid; p < NPAD; p += 256) tok[p] = 0;  // pad rows -> token 0 (never read back)
  __syncthreads();
  for (int a = tid; a < NASSIGN; a += 256) {
    const int e = idx[a];
    const int q = atomicAdd(&cur[e], 1);
    tok[q] = a >> 1;
    pos[a] = q;
  }
}

// ---------------- 128x128 BT GEMM body (2-phase dbuf, swizzled) — small proj GEMMs ----------------
template <int SB, int NT>
__device__ __forceinline__ void gemm128_body(
    const u16* __restrict__ A, const u16* __restrict__ B, void* __restrict__ C,
    int m0, int n0, int N, int K, u16* sm, int tid) {
  u16 *lA0 = sm, *lA1 = sm + 8192, *lB0 = sm + 16384, *lB1 = sm + 24576;
  const int w = tid >> 6, l = tid & 63;
  const int wm = (w >> 2) * 64, wn = (w & 3) * 32;
  const int lm = l & 15, lk = (l >> 4) * 8, xr = (l & 7) << 3;
  const int sr = l >> 3, sc = ((l & 7) ^ sr) * 8;
  const u16* As = A + (size_t)(m0 + w * 8 + sr) * K + sc;
  const u16* Bs = B + (size_t)(n0 + w * 8 + sr) * K + sc;
  f32x4 acc[4][2] = {};
  auto STG = [&](u16* dA, u16* dB, int kt) {
    g2l16(As + kt, dA + w * 512);
    g2l16(As + (size_t)64 * K + kt, dA + 4096 + w * 512);
    g2l16(Bs + kt, dB + w * 512);
    g2l16(Bs + (size_t)64 * K + kt, dB + 4096 + w * 512);
  };
  auto CMP = [&](const u16* a_, const u16* b_) {
#pragma unroll
    for (int kk = 0; kk < 2; ++kk) {
      const int ko = (kk * 32 + lk) ^ xr;
      bf16x8 af[4], bf[2];
#pragma unroll
      for (int i = 0; i < 4; ++i) af[i] = *(const bf16x8*)(a_ + (wm + i * 16 + lm) * 64 + ko);
#pragma unroll
      for (int j = 0; j < 2; ++j) bf[j] = *(const bf16x8*)(b_ + (wn + j * 16 + lm) * 64 + ko);
#pragma unroll
      for (int i = 0; i < 4; ++i)
#pragma unroll
        for (int j = 0; j < 2; ++j)
          acc[i][j] = __builtin_amdgcn_mfma_f32_16x16x32_bf16(af[i], bf[j], acc[i][j], 0, 0, 0);
    }
  };
  STG(lA0, lB0, 0);
  VMBAR();
  for (int t = 0; t < NT; t += 2) {
    if (t + 1 < NT) STG(lA1, lB1, (t + 1) * 64);
    CMP(lA0, lB0);
    VMBAR();
    if (t + 2 < NT) STG(lA0, lB0, (t + 2) * 64);
    CMP(lA1, lB1);
    VMBAR();
  }
  const int cr = (l >> 4) * 4, cc = lm;
#pragma unroll
  for (int i = 0; i < 4; ++i)
#pragma unroll
    for (int j = 0; j < 2; ++j)
#pragma unroll
      for (int r = 0; r < 4; ++r) {
        const size_t o = (size_t)(m0 + wm + i * 16 + cr + r) * N + n0 + wn + j * 16 + cc;
        if (SB) ((u16*)C)[o] = f2bf(acc[i][j][r]);
        else ((float*)C)[o] = acc[i][j][r];
      }
}

__global__ __launch_bounds__(512, 2) void ingemm_kernel(
    const u16* __restrict__ xb, const u16* __restrict__ Wib, u16* __restrict__ hb) {
  __shared__ __align__(16) u16 sm[32768];  // 64 KB
  gemm128_body<1, 8>(xb, Wib, hb, blockIdx.y * 128, blockIdx.x * 128, HDIM, HDIM, sm, threadIdx.x);
}

__global__ __launch_bounds__(512, 2) void outgemm_kernel(
    const u16* __restrict__ cb, const u16* __restrict__ Wob, float* __restrict__ out) {
  __shared__ __align__(16) u16 sm[32768];  // 64 KB
  gemm128_body<0, 8>(cb, Wob, out, blockIdx.y * 128, blockIdx.x * 128, HDIM, HDIM, sm, threadIdx.x);
}

// ---------------- gate+up GEMM, fused SiLU: 3-buffer counted-vmcnt pipeline ----------------
__global__ __launch_bounds__(512, 2) void gateup_kernel(
    const u16* __restrict__ hb, const u16* __restrict__ Wg, const u16* __restrict__ Wu,
    u16* __restrict__ act, const int* __restrict__ tok, const int* __restrict__ rbe,
    const int* __restrict__ rbp, const int* __restrict__ nrb) {
  const int rb = blockIdx.y;
  if (rb >= nrb[0]) return;
  __shared__ __align__(16) u16 sm[73728];  // 144 KB: 3 x (A 16K | G 16K | U 16K)
  const int e = rbe[rb], p0 = rbp[rb], n0 = blockIdx.x * 128;
  const int tid = threadIdx.x, w = tid >> 6, l = tid & 63;
  const int wm = (w >> 2) * 64, wn = (w & 3) * 32;
  const int lm = l & 15, lk = (l >> 4) * 8, xr = (l & 7) << 3;
  const int sr = l >> 3, sc = ((l & 7) ^ sr) * 8;
  const u16* A0 = hb + (size_t)tok[p0 + w * 8 + sr] * HDIM + sc;
  const u16* A1 = hb + (size_t)tok[p0 + 64 + w * 8 + sr] * HDIM + sc;
  const u16* G0 = Wg + (size_t)e * FDIM * HDIM + (size_t)(n0 + w * 8 + sr) * HDIM + sc;
  const u16* G1 = G0 + (size_t)64 * HDIM;
  const u16* U0 = Wu + (size_t)e * FDIM * HDIM + (size_t)(n0 + w * 8 + sr) * HDIM + sc;
  const u16* U1 = U0 + (size_t)64 * HDIM;
  f32x4 ag[4][2] = {}, au[4][2] = {};
  auto STG = [&](int b, int kt) {  // 6 vmem instrs
    u16* d = sm + b * 24576;
    g2l16(A0 + kt, d + w * 512);
    g2l16(A1 + kt, d + 4096 + w * 512);
    g2l16(G0 + kt, d + 8192 + w * 512);
    g2l16(G1 + kt, d + 12288 + w * 512);
    g2l16(U0 + kt, d + 16384 + w * 512);
    g2l16(U1 + kt, d + 20480 + w * 512);
  };
  auto CMP = [&](int b) {
    const u16* a_ = sm + b * 24576;
    const u16* g_ = a_ + 8192;
    const u16* u_ = a_ + 16384;
#pragma unroll
    for (int kk = 0; kk < 2; ++kk) {
      const int ko = (kk * 32 + lk) ^ xr;
      bf16x8 af[4], gf[2], uf[2];
#pragma unroll
      for (int i = 0; i < 4; ++i) af[i] = *(const bf16x8*)(a_ + (wm + i * 16 + lm) * 64 + ko);
#pragma unroll
      for (int j = 0; j < 2; ++j) {
        gf[j] = *(const bf16x8*)(g_ + (wn + j * 16 + lm) * 64 + ko);
        uf[j] = *(const bf16x8*)(u_ + (wn + j * 16 + lm) * 64 + ko);
      }
#pragma unroll
      for (int i = 0; i < 4; ++i)
#pragma unroll
        for (int j = 0; j < 2; ++j) {
          ag[i][j] = __builtin_amdgcn_mfma_f32_16x16x32_bf16(af[i], gf[j], ag[i][j], 0, 0, 0);
          au[i][j] = __builtin_amdgcn_mfma_f32_16x16x32_bf16(af[i], uf[j], au[i][j], 0, 0, 0);
        }
    }
  };
  STG(0, 0); STG(1, 64);
  WAITV6(); BAR();  // stage 0 landed; stage 1 in flight
#pragma unroll
  for (int t = 0; t < 8; ++t) {
    if (t + 2 < 8) STG((t + 2) % 3, (t + 2) * 64);  // issue-early
    CMP(t % 3);
    if (t + 2 < 8) WAITV6(); else WAITV0();  // stage t+1 complete; newest stays in flight
    BAR();
  }
  const int cr = (l >> 4) * 4, cc = lm;
#pragma unroll
  for (int i = 0; i < 4; ++i)
#pragma unroll
    for (int j = 0; j < 2; ++j)
#pragma unroll
      for (int r = 0; r < 4; ++r) {
        const float g = ag[i][j][r], u = au[i][j][r];
        const float s = g / (1.0f + __expf(-g));
        act[(size_t)(p0 + wm + i * 16 + cr + r) * FDIM + n0 + wn + j * 16 + cc] = f2bf(s * u);
      }
}

// ---------------- down GEMM 128x128, kk-split waves, 3-buffer pipeline, bf16 out ----------------
__global__ __launch_bounds__(512, 2) void down_kernel(
    const u16* __restrict__ act, const u16* __restrict__ Wd, u16* __restrict__ dwn,
    const int* __restrict__ rbe, const int* __restrict__ rbp, const int* __restrict__ nrb) {
  const int rb = blockIdx.y;
  if (rb >= nrb[0]) return;
  __shared__ __align__(16) u16 sm[49152];  // 96 KB: 3 x (A 16K | B 16K)
  const int e = rbe[rb], p0 = rbp[rb], n0 = blockIdx.x * 128;
  const int tid = threadIdx.x, w = tid >> 6, l = tid & 63;
  const int g = w >> 2;                         // kk-group: 0 -> k0..31, 1 -> k32..63
  const int wm = ((w >> 1) & 1) * 64, wn = (w & 1) * 64;
  const int lm = l & 15, lk = (l >> 4) * 8, xr = (l & 7) << 3;
  const int ko = (g * 32 + lk) ^ xr;
  const int sr = l >> 3, sc = ((l & 7) ^ sr) * 8;
  const u16* As = act + (size_t)(p0 + w * 8 + sr) * FDIM + sc;
  const u16* Bs = Wd + (size_t)e * HDIM * FDIM + (size_t)(n0 + w * 8 + sr) * FDIM + sc;
  f32x4 acc[4][4] = {};
  auto STG = [&](int b, int kt) {  // 4 vmem instrs
    u16* d = sm + b * 16384;
    g2l16(As + kt, d + w * 512);
    g2l16(As + (size_t)64 * FDIM + kt, d + 4096 + w * 512);
    g2l16(Bs + kt, d + 8192 + w * 512);
    g2l16(Bs + (size_t)64 * FDIM + kt, d + 12288 + w * 512);
  };
  auto CMP = [&](int b) {
    const u16* a_ = sm + b * 16384;
    const u16* b_ = a_ + 8192;
    bf16x8 af[4], bf[4];
#pragma unroll
    for (int i = 0; i < 4; ++i) af[i] = *(const bf16x8*)(a_ + (wm + i * 16 + lm) * 64 + ko);
#pragma unroll
    for (int j = 0; j < 4; ++j) bf[j] = *(const bf16x8*)(b_ + (wn + j * 16 + lm) * 64 + ko);
#pragma unroll
    for (int i = 0; i < 4; ++i)
#pragma unroll
      for (int j = 0; j < 4; ++j)
        acc[i][j] = __builtin_amdgcn_mfma_f32_16x16x32_bf16(af[i], bf[j], acc[i][j], 0, 0, 0);
  };
  STG(0, 0); STG(1, 64);
  WAITV4(); BAR();
#pragma unroll
  for (int t = 0; t < 32; ++t) {
    if (t + 2 < 32) STG((t + 2) % 3, (t + 2) * 64);
    CMP(t % 3);
    if (t + 2 < 32) WAITV4(); else WAITV0();
    BAR();
  }
  // partner-wave reduction: waves 4-7 (kk=1) dump partials; waves 0-3 add + store
  asm volatile("s_waitcnt lgkmcnt(0)" ::: "memory");
  __builtin_amdgcn_sched_barrier(0);
  BAR();
  float* red = (float*)sm;
  if (g == 1) {
#pragma unroll
    for (int i = 0; i < 4; ++i)
#pragma unroll
      for (int j = 0; j < 4; ++j)
        *(f32x4*)&red[(w & 3) * 4096 + (i * 4 + j) * 256 + l * 4] = acc[i][j];
  }
  BAR();
  if (g == 0) {
    const int cr = (l >> 4) * 4, cc = lm;
#pragma unroll
    for (int i = 0; i < 4; ++i)
#pragma unroll
      for (int j = 0; j < 4; ++j) {
        const f32x4 o = *(const f32x4*)&red[w * 4096 + (i * 4 + j) * 256 + l * 4];
        const f32x4 s = acc[i][j] + o;
#pragma unroll
        for (int r = 0; r < 4; ++r)
          dwn[(size_t)(p0 + wm + i * 16 + cr + r) * HDIM + n0 + wn + j * 16 + cc] = f2bf(s[r]);
      }
  }
}

// ---------------- combine: c[n] = w0*down[pos0] + w1*down[pos1] (bf16 in/out) ----------------
__global__ void combine_kernel(const u16* __restrict__ dwn, const int* __restrict__ pos,
                               const float* __restrict__ wts, u16* __restrict__ cb) {
  const int n = blockIdx.x, t = threadIdx.x;  // 128 threads x 4 elems
  const int p0 = pos[2 * n], p1 = pos[2 * n + 1];
  const float w0 = wts[2 * n], w1 = wts[2 * n + 1];
  const ushort4 a = ((const ushort4*)(dwn + (size_t)p0 * HDIM))[t];
  const ushort4 b = ((const ushort4*)(dwn + (size_t)p1 * HDIM))[t];
  ushort4 o;
  o.x = f2bf(w0 * bf2f(a.x) + w1 * bf2f(b.x));
  o.y = f2bf(w0 * bf2f(a.y) + w1 * bf2f(b.y));
  o.z = f2bf(w0 * bf2f(a.z) + w1 * bf2f(b.z));
  o.w = f2bf(w0 * bf2f(a.w) + w1 * bf2f(b.w));
  ((ushort4*)(cb + (size_t)n * HDIM))[t] = o;
}

extern "C" void kernel_launch(void* const* d_in, const int* in_sizes, int n_in,
                              void* d_out, int out_size, void* d_ws, size_t ws_size,
                              hipStream_t stream) {
  const float* x  = (const float*)d_in[0];
  const float* Wi = (const float*)d_in[1];
  const float* Wr = (const float*)d_in[2];
  const float* Wg = (const float*)d_in[3];
  const float* Wu = (const float*)d_in[4];
  const float* Wd = (const float*)d_in[5];
  const float* Wo = (const float*)d_in[6];
  float* out = (float*)d_out;

  char* ws = (char*)d_ws;
  size_t off = 0;
  auto alloc = [&](size_t bytes) -> void* {
    off = (off + 255) & ~(size_t)255;
    void* p = ws + off;
    off += bytes;
    return p;
  };
  u16* xb  = (u16*)alloc((size_t)NTOK * HDIM * 2);
  u16* hb  = (u16*)alloc((size_t)NTOK * HDIM * 2);
  u16* cb  = (u16*)alloc((size_t)NTOK * HDIM * 2);
  u16* Wib = (u16*)alloc((size_t)HDIM * HDIM * 2);
  u16* Wob = (u16*)alloc((size_t)HDIM * HDIM * 2);
  u16* Wgb = (u16*)alloc((size_t)NEXP * FDIM * HDIM * 2);
  u16* Wub = (u16*)alloc((size_t)NEXP * FDIM * HDIM * 2);
  u16* Wdb = (u16*)alloc((size_t)NEXP * HDIM * FDIM * 2);
  u16* actb = (u16*)alloc((size_t)NPAD * FDIM * 2);
  u16* dwn = (u16*)alloc((size_t)NPAD * HDIM * 2);
  double* wre = (double*)alloc((size_t)NEXP * HDIM * 8);
  int* idx = (int*)alloc((size_t)NASSIGN * 4);
  float* wts = (float*)alloc((size_t)NASSIGN * 4);
  int* tok = (int*)alloc((size_t)NPAD * 4);
  int* pos = (int*)alloc((size_t)NASSIGN * 4);
  int* rbe = (int*)alloc((size_t)RBMAX * 4);
  int* rbp = (int*)alloc((size_t)RBMAX * 4);
  int* nrb = (int*)alloc(256);

  cvtall_kernel<<<6784, 256, 0, stream>>>(x, Wi, Wo, Wg, Wu, Wd, xb, Wib, Wob, Wgb, Wub, Wdb);
  wreff_kernel<<<16, 256, 0, stream>>>(Wr, Wi, wre);
  router_kernel<<<16, 256, 0, stream>>>(x, wre, idx, wts);
  assign_kernel<<<1, 256, 0, stream>>>(idx, tok, pos, rbe, rbp, nrb);
  ingemm_kernel<<<dim3(4, 32), 512, 0, stream>>>(xb, Wib, hb);
  gateup_kernel<<<dim3(16, 72), 512, 0, stream>>>(hb, Wgb, Wub, actb, tok, rbe, rbp, nrb);
  down_kernel<<<dim3(4, 72), 512, 0, stream>>>(actb, Wdb, dwn, rbe, rbp, nrb);
  combine_kernel<<<NTOK, 128, 0, stream>>>(dwn, pos, wts, cb);
  outgemm_kernel<<<dim3(4, 32), 512, 0, stream>>>(cb, Wob, out);
}